// Round 10
// baseline (53.712 us; speedup 1.0000x reference)
//
#include <hip/hip_runtime.h>
#include <math.h>

#define BB 2048
#define DD 512
#define NS 7
#define KK 1024   // GEMM K (elements == bytes in fp8)
#define BM 128
#define BN 64
#define BK 64
#define NT (KK / BK)  // 16 K-steps

typedef __attribute__((ext_vector_type(4))) float floatx4;
typedef long long i64;
typedef unsigned long long u64;

typedef const __attribute__((address_space(1))) void gv_t;
typedef __attribute__((address_space(3))) void lv_t;
__device__ __forceinline__ void gl2lds16(const void* g, void* l) {
  __builtin_amdgcn_global_load_lds((gv_t*)g, (lv_t*)l, 16, 0, 0);
}

// monotone float<->uint key for atomicMax over signed floats
__device__ __forceinline__ unsigned fkey(float f) {
  unsigned u = __float_as_uint(f);
  return (u & 0x80000000u) ? ~u : (u | 0x80000000u);
}
__device__ __forceinline__ float funkey(unsigned k) {
  unsigned u = (k & 0x80000000u) ? (k ^ 0x80000000u) : ~k;
  return __uint_as_float(u);
}

// 8 floats -> 8 fp8 e4m3 (OCP, RNE)
__device__ __forceinline__ uint2 pack8_fp8(const float* v) {
  int lo = 0, hi = 0;
  lo = __builtin_amdgcn_cvt_pk_fp8_f32(v[0], v[1], lo, false);
  lo = __builtin_amdgcn_cvt_pk_fp8_f32(v[2], v[3], lo, true);
  hi = __builtin_amdgcn_cvt_pk_fp8_f32(v[4], v[5], hi, false);
  hi = __builtin_amdgcn_cvt_pk_fp8_f32(v[6], v[7], hi, true);
  uint2 r; r.x = (unsigned)lo; r.y = (unsigned)hi; return r;
}

__device__ __forceinline__ float wsum(float v) {
#pragma unroll
  for (int off = 32; off > 0; off >>= 1) v += __shfl_xor(v, off, 64);
  return v;
}

// ---------------------------------------------------------------------------
// Kernel 1: wave-per-row prep (round-9, unchanged math) + zero all cross-block
// accumulators/counters for this replay (harness does not re-poison).
__global__ __launch_bounds__(256) void prep(
    const float* __restrict__ qmean, const float* __restrict__ qls,
    const float* __restrict__ tmean, const float* __restrict__ tls,
    const float* __restrict__ eps,
    unsigned char* __restrict__ Acat, unsigned char* __restrict__ Bcat,
    float* __restrict__ qterm, unsigned* __restrict__ Mkey,
    unsigned* __restrict__ rmax, u64* __restrict__ rowsum,
    unsigned* __restrict__ cnt) {
  const int w = threadIdx.x >> 6, lane = threadIdx.x & 63;
  const int r = blockIdx.x * 4 + w;  // 0..4095
  const int grp = (lane >> 3) * 64;
  const int physoff = (((((lane & 7) >> 1) ^ r) & 3) << 4) |
                      ((((lane & 7) ^ (r >> 2)) & 1) << 3);
  if (r < BB) {
    const int q = r;
    if (q == 0) {  // zero sync counters (block 0, wave 0)
      cnt[lane] = 0u;
      cnt[64 + lane] = 0u;
    }
    const float4* xm = (const float4*)(qmean + (size_t)q * DD);
    const float4* xl = (const float4*)(qls + (size_t)q * DD);
    float4 a0 = xm[2 * lane], a1 = xm[2 * lane + 1];
    float4 l0 = xl[2 * lane], l1 = xl[2 * lane + 1];
    float x[8] = {a0.x, a0.y, a0.z, a0.w, a1.x, a1.y, a1.z, a1.w};
    float l[8] = {l0.x, l0.y, l0.z, l0.w, l1.x, l1.y, l1.z, l1.w};
    float ss = 0.f;
#pragma unroll
    for (int e = 0; e < 8; ++e) ss += x[e] * x[e];
    ss = wsum(ss);
    float inv = 1.0f / fmaxf(sqrtf(ss), 1e-12f);
    float W[8], M2[8], qt = 0.f;
#pragma unroll
    for (int e = 0; e < 8; ++e) {
      W[e] = expf(-l[e]);
      float n = x[e] * inv;
      M2[e] = -2.0f * n * W[e];
      qt += n * n * W[e];
    }
    qt = wsum(qt);
    if (lane == 0) qterm[q] = qt;
    unsigned char* arow = Acat + (size_t)q * KK;
    *(uint2*)(arow + grp + physoff)       = pack8_fp8(W);
    *(uint2*)(arow + 512 + grp + physoff) = pack8_fp8(M2);
  } else {
    const int t = r - BB;
    if (lane == 0) {
      Mkey[t] = 0u;    // below fkey of any finite float
      rmax[t] = 0u;
      rowsum[t] = 0ull;
    }
    const float4* xm = (const float4*)(tmean + (size_t)t * DD);
    const float4* xl = (const float4*)(tls + (size_t)t * DD);
    float4 a0 = xm[2 * lane], a1 = xm[2 * lane + 1];
    float4 l0 = xl[2 * lane], l1 = xl[2 * lane + 1];
    float x[8] = {a0.x, a0.y, a0.z, a0.w, a1.x, a1.y, a1.z, a1.w};
    float l[8] = {l0.x, l0.y, l0.z, l0.w, l1.x, l1.y, l1.z, l1.w};
    float ss = 0.f;
#pragma unroll
    for (int e = 0; e < 8; ++e) ss += x[e] * x[e];
    ss = wsum(ss);
    float inv = 1.0f / fmaxf(sqrtf(ss), 1e-12f);
    float se[8], sq[8];
#pragma unroll
    for (int e = 0; e < 8; ++e) { se[e] = 0.f; sq[e] = 0.f; }
    const float4* ep = (const float4*)(eps + (size_t)t * NS * DD);
#pragma unroll
    for (int s = 0; s < NS; ++s) {
      float4 e0 = ep[s * (DD / 4) + 2 * lane];
      float4 e1 = ep[s * (DD / 4) + 2 * lane + 1];
      float ev[8] = {e0.x, e0.y, e0.z, e0.w, e1.x, e1.y, e1.z, e1.w};
#pragma unroll
      for (int e = 0; e < 8; ++e) { se[e] += ev[e]; sq[e] += ev[e] * ev[e]; }
    }
    const float i7 = 1.0f / 7.0f;
    float S2[8], S1[8];
#pragma unroll
    for (int e = 0; e < 8; ++e) {
      float tm = x[e] * inv;
      float sg = expf(l[e]);
      float m1 = sg * se[e] * i7;
      S1[e] = tm + m1;
      S2[e] = (tm * tm + 2.0f * tm * m1 + sg * sg * sq[e] * i7) * 0.00390625f;
    }
    unsigned char* brow = Bcat + (size_t)t * KK;
    *(uint2*)(brow + grp + physoff)       = pack8_fp8(S2);
    *(uint2*)(brow + 512 + grp + physoff) = pack8_fp8(S1);
  }
}

// ---------------------------------------------------------------------------
// Kernel 2: fused GEMM + colmax + row-LSE + loss. 512 blocks x 256 threads.
// Co-residency guaranteed: LDS ~37KB -> 4 blocks/CU; VGPR <= 256 -> >= 2
// blocks/CU; 256 CUs x 2 >= 512. Grid sync = hierarchical arrive (32+1
// counters, zeroed each replay by prep) + bounded spin on pure atomic loads.
// All cross-block data moves via device-scope atomics (coherent at MALL).
__global__ __launch_bounds__(256) void fused_loss(
    const unsigned char* __restrict__ Acat,
    const unsigned char* __restrict__ Bcat,
    const float* __restrict__ qterm,
    unsigned* __restrict__ Mkey, unsigned* __restrict__ rmax,
    unsigned* __restrict__ diagv, u64* __restrict__ rowsum,
    unsigned* __restrict__ cnt, float* __restrict__ out) {
  __shared__ __align__(16) char As[3][BM * BK];  // 3 x 8 KB
  __shared__ __align__(16) char Bs[3][BN * BK];  // 3 x 4 KB
  __shared__ unsigned mk[64];
  __shared__ float rmx[128];
  __shared__ float sb[4];
  const int tid = threadIdx.x, lane = tid & 63, wid = tid >> 6;
  const int bid = blockIdx.x;                           // 0..511
  const int xcd = bid & 7, j = bid >> 3;
  const int tr = ((xcd >> 2) << 3) + (j >> 3);          // tile row 0..15
  const int tc = ((xcd & 3) << 3) + (j & 7);            // tile col 0..31
  const int brow = tr * BM, bcol = tc * BN;
  const int wr = wid >> 1, wc = wid & 1;                // wave 64x32 sub-tile
  const int fr = lane & 15, kg = lane >> 4;

  floatx4 acc[2][4][2];
#pragma unroll
  for (int h = 0; h < 2; ++h)
#pragma unroll
    for (int m = 0; m < 4; ++m)
#pragma unroll
      for (int n = 0; n < 2; ++n) acc[h][m][n] = (floatx4){0.f, 0.f, 0.f, 0.f};

  const unsigned char* gA0 = Acat + (size_t)(brow + (tid >> 2)) * KK + (tid & 3) * 16;
  const unsigned char* gA1 = gA0 + (size_t)64 * KK;
  const unsigned char* gB0 = Bcat + (size_t)(bcol + (tid >> 2)) * KK + (tid & 3) * 16;

#define STAGE(buf, kc)                                      \
  {                                                         \
    gl2lds16(gA0 + (kc), &As[buf][tid * 16]);               \
    gl2lds16(gA1 + (kc), &As[buf][4096 + tid * 16]);        \
    gl2lds16(gB0 + (kc), &Bs[buf][tid * 16]);               \
  }

  STAGE(0, 0)
  STAGE(1, BK)

#pragma unroll
  for (int kt = 0; kt < NT; ++kt) {
    if (kt < NT - 1) asm volatile("s_waitcnt vmcnt(3)" ::: "memory");
    else             asm volatile("s_waitcnt vmcnt(0)" ::: "memory");
    __builtin_amdgcn_s_barrier();
    if (kt + 2 < NT) { STAGE((kt + 2) % 3, (kt + 2) * BK) }
    const char* a  = As[kt % 3];
    const char* bp = Bs[kt % 3];
#pragma unroll
    for (int kh = 0; kh < 2; ++kh) {
      const int co = ((((kh * 2 + (kg >> 1)) ^ fr) & 3) << 4) |
                     (((kg ^ (fr >> 2)) & 1) << 3);
      i64 af[4], bf[2];
#pragma unroll
      for (int m = 0; m < 4; ++m)
        af[m] = *(const i64*)(a + (wr * 64 + m * 16 + fr) * BK + co);
#pragma unroll
      for (int n = 0; n < 2; ++n)
        bf[n] = *(const i64*)(bp + (wc * 32 + n * 16 + fr) * BK + co);
      __builtin_amdgcn_s_setprio(1);
#pragma unroll
      for (int m = 0; m < 4; ++m)
#pragma unroll
        for (int n = 0; n < 2; ++n)
          acc[kt >> 3][m][n] = __builtin_amdgcn_mfma_f32_16x16x32_fp8_fp8(
              af[m], bf[n], acc[kt >> 3][m][n], 0, 0, 0);
      __builtin_amdgcn_s_setprio(0);
    }
  }
#undef STAGE

  // combine split halves + qterm -> cv holds v = loc value
  floatx4 cv[4][2];
#pragma unroll
  for (int m = 0; m < 4; ++m) {
    const int row = brow + wr * 64 + m * 16 + kg * 4;
#pragma unroll
    for (int r4 = 0; r4 < 4; ++r4) {
      float qt = qterm[row + r4];
#pragma unroll
      for (int n = 0; n < 2; ++n)
        cv[m][n][r4] = -0.5f * (256.0f * acc[0][m][n][r4] + acc[1][m][n][r4] + qt);
    }
  }
  // column max -> Mkey (order-invariant atomicMax on encoded keys)
#pragma unroll
  for (int n = 0; n < 2; ++n) {
    float cm = -3.402823466e38f;
#pragma unroll
    for (int m = 0; m < 4; ++m)
#pragma unroll
      for (int r4 = 0; r4 < 4; ++r4) cm = fmaxf(cm, cv[m][n][r4]);
    cm = fmaxf(cm, __shfl_xor(cm, 16, 64));
    cm = fmaxf(cm, __shfl_xor(cm, 32, 64));
    if (kg == 0) atomicMax(&Mkey[bcol + wc * 32 + n * 16 + fr], fkey(cm));
  }

  // ---- grid sync S1 (colmax complete) ----
  __syncthreads();  // drains each thread's atomics (vmcnt0 before barrier)
  if (tid == 0) {
    unsigned v = atomicAdd(&cnt[bid & 31], 1u);
    if (v == 15u) atomicAdd(&cnt[32], 1u);
    for (int it = 0; it < (1 << 20); ++it) {
      if (__hip_atomic_load(&cnt[32], __ATOMIC_RELAXED,
                            __HIP_MEMORY_SCOPE_AGENT) >= 32u) break;
      __builtin_amdgcn_s_sleep(4);
    }
  }
  __syncthreads();

  // coherent snapshot of this block's 64 column maxima
  if (tid < 64) mk[tid] = atomicMax(&Mkey[bcol + tid], 0u);
  __syncthreads();
  const float Mn0 = funkey(mk[wc * 32 + fr]);
  const float Mn1 = funkey(mk[wc * 32 + 16 + fr]);
  const int col0 = bcol + wc * 32 + fr, col1 = col0 + 16;

  // x = v - M[col]; diag via atomicExch (device-coherent); row max atomicMax
#pragma unroll
  for (int m = 0; m < 4; ++m) {
#pragma unroll
    for (int r4 = 0; r4 < 4; ++r4) {
      const int row = brow + wr * 64 + m * 16 + kg * 4 + r4;
      float x0 = cv[m][0][r4] - Mn0;
      float x1 = cv[m][1][r4] - Mn1;
      cv[m][0][r4] = x0; cv[m][1][r4] = x1;
      if (row == col0) atomicExch(&diagv[row], __float_as_uint(x0));
      if (row == col1) atomicExch(&diagv[row], __float_as_uint(x1));
      float xm = fmaxf(x0, x1);
      xm = fmaxf(xm, __shfl_xor(xm, 1, 64));
      xm = fmaxf(xm, __shfl_xor(xm, 2, 64));
      xm = fmaxf(xm, __shfl_xor(xm, 4, 64));
      xm = fmaxf(xm, __shfl_xor(xm, 8, 64));
      if (fr == 0) atomicMax(&rmax[row], fkey(xm));
    }
  }

  // ---- grid sync S2 (row maxima complete) ----
  __syncthreads();
  if (tid == 0) {
    unsigned v = atomicAdd(&cnt[33 + (bid & 31)], 1u);
    if (v == 15u) atomicAdd(&cnt[65], 1u);
    for (int it = 0; it < (1 << 20); ++it) {
      if (__hip_atomic_load(&cnt[65], __ATOMIC_RELAXED,
                            __HIP_MEMORY_SCOPE_AGENT) >= 32u) break;
      __builtin_amdgcn_s_sleep(4);
    }
  }
  __syncthreads();

  if (tid < 128) rmx[tid] = funkey(atomicMax(&rmax[brow + tid], 0u));
  __syncthreads();

  // exp-sum into fixed-point (2^44) u64 accumulators: order-invariant
#pragma unroll
  for (int m = 0; m < 4; ++m) {
#pragma unroll
    for (int r4 = 0; r4 < 4; ++r4) {
      const int rloc = wr * 64 + m * 16 + kg * 4 + r4;
      const float rm = rmx[rloc];
      float e = expf(cv[m][0][r4] - rm) + expf(cv[m][1][r4] - rm);
      e += __shfl_xor(e, 1, 64);
      e += __shfl_xor(e, 2, 64);
      e += __shfl_xor(e, 4, 64);
      e += __shfl_xor(e, 8, 64);
      if (fr == 0)
        atomicAdd(&rowsum[brow + rloc], (u64)(e * 1.7592186044416e13f));
    }
  }

  // ---- sync S3 arrive (only block 0 spins) ----
  __syncthreads();
  if (tid == 0) {
    unsigned v = atomicAdd(&cnt[66 + (bid & 31)], 1u);
    if (v == 15u) atomicAdd(&cnt[98], 1u);
    if (bid == 0) {
      for (int it = 0; it < (1 << 20); ++it) {
        if (__hip_atomic_load(&cnt[98], __ATOMIC_RELAXED,
                              __HIP_MEMORY_SCOPE_AGENT) >= 32u) break;
        __builtin_amdgcn_s_sleep(4);
      }
    }
  }
  __syncthreads();
  if (bid != 0) return;

  // final: loss = -mean_q( diag[q] - rmax[q] - log(rowsum[q]) )
  float s = 0.f;
#pragma unroll
  for (int i = 0; i < 8; ++i) {
    int q = tid + i * 256;
    float dg = __uint_as_float(diagv[q]);
    float rm = funkey(rmax[q]);
    float rs = (float)rowsum[q] * 5.6843418860808015e-14f;  // 2^-44
    s += dg - rm - logf(rs);
  }
  s = wsum(s);
  if (lane == 0) sb[wid] = s;
  __syncthreads();
  if (tid == 0) out[0] = -(sb[0] + sb[1] + sb[2] + sb[3]) * (1.0f / (float)BB);
}

// ---------------------------------------------------------------------------
extern "C" void kernel_launch(void* const* d_in, const int* in_sizes, int n_in,
                              void* d_out, int out_size, void* d_ws, size_t ws_size,
                              hipStream_t stream) {
  const float* qmean = (const float*)d_in[0];
  const float* qls   = (const float*)d_in[1];
  // d_in[2] query_z: cancels (broadcasts on target axis -> drops in colmax+softmax)
  const float* tmean = (const float*)d_in[3];
  const float* tls   = (const float*)d_in[4];
  // d_in[5] target_z: unused by reference
  const float* eps   = (const float*)d_in[6];

  char* ws = (char*)d_ws;
  unsigned char* Acat = (unsigned char*)(ws);                        // 2 MB
  unsigned char* Bcat = (unsigned char*)(ws + (2u << 20));           // 2 MB
  float* qterm  = (float*)(ws + (4u << 20));                         // 8 KB
  unsigned* Mkey = (unsigned*)(ws + (4u << 20) + 8192);              // 8 KB
  unsigned* rmax = (unsigned*)(ws + (4u << 20) + 16384);             // 8 KB
  unsigned* diagv = (unsigned*)(ws + (4u << 20) + 24576);            // 8 KB
  u64* rowsum = (u64*)(ws + (4u << 20) + 32768);                     // 16 KB
  unsigned* cnt = (unsigned*)(ws + (4u << 20) + 49152);              // 512 B

  prep<<<1024, 256, 0, stream>>>(qmean, qls, tmean, tls, eps,
                                 Acat, Bcat, qterm, Mkey, rmax, rowsum, cnt);
  fused_loss<<<512, 256, 0, stream>>>(Acat, Bcat, qterm, Mkey, rmax, diagv,
                                      rowsum, cnt, (float*)d_out);
}

// Round 11
// 39.588 us; speedup vs baseline: 1.3568x; 1.3568x over previous
//
#include <hip/hip_runtime.h>
#include <math.h>

#define BB 2048
#define DD 512
#define NS 7
#define KK 1024   // GEMM K (elements == bytes in fp8)
#define BM 128
#define BN 64
#define BK 128
#define NT (KK / BK)  // 8 K-steps

typedef __attribute__((ext_vector_type(8))) short short8;
typedef __attribute__((ext_vector_type(4))) float floatx4;
typedef long long i64;
typedef unsigned long long u64;

typedef const __attribute__((address_space(1))) void gv_t;
typedef __attribute__((address_space(3))) void lv_t;
__device__ __forceinline__ void gl2lds16(const void* g, void* l) {
  __builtin_amdgcn_global_load_lds((gv_t*)g, (lv_t*)l, 16, 0, 0);
}

__device__ __forceinline__ unsigned short f2bf(float f) {
  unsigned int u = __float_as_uint(f);
  u += 0x7FFFu + ((u >> 16) & 1u);  // RNE
  return (unsigned short)(u >> 16);
}
__device__ __forceinline__ float bf2f(unsigned short u) {
  return __uint_as_float(((unsigned)u) << 16);
}

// monotone float<->uint key for atomicMax over signed floats
__device__ __forceinline__ unsigned fkey(float f) {
  unsigned u = __float_as_uint(f);
  return (u & 0x80000000u) ? ~u : (u | 0x80000000u);
}
__device__ __forceinline__ float funkey(unsigned k) {
  unsigned u = (k & 0x80000000u) ? (k ^ 0x80000000u) : ~k;
  return __uint_as_float(u);
}

// 8 floats -> 8 fp8 e4m3 (OCP, RNE)
__device__ __forceinline__ uint2 pack8_fp8(const float* v) {
  int lo = 0, hi = 0;
  lo = __builtin_amdgcn_cvt_pk_fp8_f32(v[0], v[1], lo, false);
  lo = __builtin_amdgcn_cvt_pk_fp8_f32(v[2], v[3], lo, true);
  hi = __builtin_amdgcn_cvt_pk_fp8_f32(v[4], v[5], hi, false);
  hi = __builtin_amdgcn_cvt_pk_fp8_f32(v[6], v[7], hi, true);
  uint2 r; r.x = (unsigned)lo; r.y = (unsigned)hi; return r;
}

// XOR-16 swizzle: within each 128B K-chunk of a row, 8B-unit j is stored at
// physical unit j ^ (row&15). ds_read_b64 bank-pair = unit index (row stride
// 128B contributes no bank bits), so a wave's 64 reads claim each of the 16
// bank-pairs exactly 4x = the b64 floor. Producer writes it; linear
// global_load_lds staging preserves it; fragment reads un-XOR.

__device__ __forceinline__ float wsum(float v) {
#pragma unroll
  for (int off = 32; off > 0; off >>= 1) v += __shfl_xor(v, off, 64);
  return v;
}
__device__ __forceinline__ float wmax(float v) {
#pragma unroll
  for (int off = 32; off > 0; off >>= 1) v = fmaxf(v, __shfl_xor(v, off, 64));
  return v;
}

// ---------------------------------------------------------------------------
// Kernel 1: wave-per-row prep. 1024 blocks x 4 waves.
// Rows [0,2048) = query q; [2048,4096) = target t.
// A[q][k]: k<512 -> W=exp(-qls); k>=512 -> -2*qm_n*W.   (fp8, XOR-16 swizzled)
// B[t][k]: k<512 -> S2*(1/256);  k>=512 -> S1.          (fp8, XOR-16 swizzled)
// Also zeros Mkey and the arrive counters for this replay.
__global__ __launch_bounds__(256) void prep(
    const float* __restrict__ qmean, const float* __restrict__ qls,
    const float* __restrict__ tmean, const float* __restrict__ tls,
    const float* __restrict__ eps,
    unsigned char* __restrict__ Acat, unsigned char* __restrict__ Bcat,
    float* __restrict__ qterm, unsigned* __restrict__ Mkey,
    unsigned* __restrict__ cnt) {
  const int w = threadIdx.x >> 6, lane = threadIdx.x & 63;
  const int r = blockIdx.x * 4 + w;  // 0..4095
  // lane handles 8 consecutive elements: 128B chunk c = lane>>4, unit j = lane&15
  const int grp = (lane >> 4) * 128;
  const int physoff = ((lane & 15) ^ (r & 15)) << 3;
  if (r < BB) {
    const int q = r;
    if (q == 0) cnt[lane] = 0u;  // zero arrive counters (uses [0..32])
    const float4* xm = (const float4*)(qmean + (size_t)q * DD);
    const float4* xl = (const float4*)(qls + (size_t)q * DD);
    float4 a0 = xm[2 * lane], a1 = xm[2 * lane + 1];
    float4 l0 = xl[2 * lane], l1 = xl[2 * lane + 1];
    float x[8] = {a0.x, a0.y, a0.z, a0.w, a1.x, a1.y, a1.z, a1.w};
    float l[8] = {l0.x, l0.y, l0.z, l0.w, l1.x, l1.y, l1.z, l1.w};
    float ss = 0.f;
#pragma unroll
    for (int e = 0; e < 8; ++e) ss += x[e] * x[e];
    ss = wsum(ss);
    float inv = 1.0f / fmaxf(sqrtf(ss), 1e-12f);
    float W[8], M2[8], qt = 0.f;
#pragma unroll
    for (int e = 0; e < 8; ++e) {
      W[e] = expf(-l[e]);
      float n = x[e] * inv;
      M2[e] = -2.0f * n * W[e];
      qt += n * n * W[e];
    }
    qt = wsum(qt);
    if (lane == 0) qterm[q] = qt;
    unsigned char* arow = Acat + (size_t)q * KK;
    *(uint2*)(arow + grp + physoff)       = pack8_fp8(W);
    *(uint2*)(arow + 512 + grp + physoff) = pack8_fp8(M2);
  } else {
    const int t = r - BB;
    if (lane == 0) Mkey[t] = 0u;  // below fkey of any finite float
    const float4* xm = (const float4*)(tmean + (size_t)t * DD);
    const float4* xl = (const float4*)(tls + (size_t)t * DD);
    float4 a0 = xm[2 * lane], a1 = xm[2 * lane + 1];
    float4 l0 = xl[2 * lane], l1 = xl[2 * lane + 1];
    float x[8] = {a0.x, a0.y, a0.z, a0.w, a1.x, a1.y, a1.z, a1.w};
    float l[8] = {l0.x, l0.y, l0.z, l0.w, l1.x, l1.y, l1.z, l1.w};
    float ss = 0.f;
#pragma unroll
    for (int e = 0; e < 8; ++e) ss += x[e] * x[e];
    ss = wsum(ss);
    float inv = 1.0f / fmaxf(sqrtf(ss), 1e-12f);
    float se[8], sq[8];
#pragma unroll
    for (int e = 0; e < 8; ++e) { se[e] = 0.f; sq[e] = 0.f; }
    const float4* ep = (const float4*)(eps + (size_t)t * NS * DD);
#pragma unroll
    for (int s = 0; s < NS; ++s) {
      float4 e0 = ep[s * (DD / 4) + 2 * lane];
      float4 e1 = ep[s * (DD / 4) + 2 * lane + 1];
      float ev[8] = {e0.x, e0.y, e0.z, e0.w, e1.x, e1.y, e1.z, e1.w};
#pragma unroll
      for (int e = 0; e < 8; ++e) { se[e] += ev[e]; sq[e] += ev[e] * ev[e]; }
    }
    const float i7 = 1.0f / 7.0f;
    float S2[8], S1[8];
#pragma unroll
    for (int e = 0; e < 8; ++e) {
      float tm = x[e] * inv;
      float sg = expf(l[e]);
      float m1 = sg * se[e] * i7;
      S1[e] = tm + m1;
      S2[e] = (tm * tm + 2.0f * tm * m1 + sg * sg * sq[e] * i7) * 0.00390625f;
    }
    unsigned char* brow = Bcat + (size_t)t * KK;
    *(uint2*)(brow + grp + physoff)       = pack8_fp8(S2);
    *(uint2*)(brow + 512 + grp + physoff) = pack8_fp8(S1);
  }
}

// ---------------------------------------------------------------------------
// Kernel 2 (round-11): fp8 GEMM, 128x64 tile, 4 waves, grid 512 (2/CU).
// BK=128: 8 K-steps (half the barriers of round 9). Triple-buffered LDS
// (72 KB -> still 2 blocks/CU) via global_load_lds; counted vmcnt(6);
// setprio; XCD 8x8 rectangles; XOR-16 conflict-free fragment reads.
// Split accumulators: kt<4 (S2 half, x256) vs kt>=4 (S1 half).
__global__ __launch_bounds__(256) void gemm_loc(
    const unsigned char* __restrict__ Acat,
    const unsigned char* __restrict__ Bcat,
    const float* __restrict__ qterm,
    unsigned short* __restrict__ loc, unsigned* __restrict__ Mkey) {
  __shared__ __align__(16) char As[3][BM * BK];  // 3 x 16 KB
  __shared__ __align__(16) char Bs[3][BN * BK];  // 3 x  8 KB
  const int tid = threadIdx.x, lane = tid & 63, wid = tid >> 6;
  const int lin = blockIdx.y * (BB / BN) + blockIdx.x;  // 0..511
  const int xcd = lin & 7, j = lin >> 3;
  const int tr = ((xcd >> 2) << 3) + (j >> 3);          // tile row 0..15
  const int tc = ((xcd & 3) << 3) + (j & 7);            // tile col 0..31
  const int brow = tr * BM, bcol = tc * BN;
  const int wr = wid >> 1, wc = wid & 1;                // wave 64x32 sub-tile
  const int fr = lane & 15, kg = lane >> 4;

  floatx4 acc[2][4][2];
#pragma unroll
  for (int h = 0; h < 2; ++h)
#pragma unroll
    for (int m = 0; m < 4; ++m)
#pragma unroll
      for (int n = 0; n < 2; ++n) acc[h][m][n] = (floatx4){0.f, 0.f, 0.f, 0.f};

  // staging: thread covers row tid>>3 (+32/64/96 for A, +32 for B), 16B @ (tid&7)*16
  const unsigned char* gA0 = Acat + (size_t)(brow + (tid >> 3)) * KK + (tid & 7) * 16;
  const unsigned char* gB0 = Bcat + (size_t)(bcol + (tid >> 3)) * KK + (tid & 7) * 16;
  const int ldst = (tid >> 3) * 128 + (tid & 7) * 16;  // == tid*16 (lane-linear)

#define STAGE(buf, kc)                                                   \
  {                                                                      \
    _Pragma("unroll")                                                    \
    for (int j2 = 0; j2 < 4; ++j2)                                       \
      gl2lds16(gA0 + (size_t)j2 * 32 * KK + (kc), &As[buf][ldst + j2 * 4096]); \
    _Pragma("unroll")                                                    \
    for (int j2 = 0; j2 < 2; ++j2)                                       \
      gl2lds16(gB0 + (size_t)j2 * 32 * KK + (kc), &Bs[buf][ldst + j2 * 4096]); \
  }

  STAGE(0, 0)
  STAGE(1, BK)

#pragma unroll
  for (int kt = 0; kt < NT; ++kt) {
    // own tile-kt's 6 loads landed; tile kt+1's 6 may stay in flight
    if (kt < NT - 1) asm volatile("s_waitcnt vmcnt(6)" ::: "memory");
    else             asm volatile("s_waitcnt vmcnt(0)" ::: "memory");
    __builtin_amdgcn_s_barrier();
    if (kt + 2 < NT) { STAGE((kt + 2) % 3, (kt + 2) * BK) }
    const char* a  = As[kt % 3];
    const char* bp = Bs[kt % 3];
#pragma unroll
    for (int kh = 0; kh < 4; ++kh) {
      // logical 8B unit u = kh*4+kg, stored at u ^ (row&15); row&15 == fr
      const int co = (((kh * 4 + kg) ^ fr) & 15) << 3;
      i64 af[4], bf[2];
#pragma unroll
      for (int m = 0; m < 4; ++m)
        af[m] = *(const i64*)(a + (wr * 64 + m * 16 + fr) * BK + co);
#pragma unroll
      for (int n = 0; n < 2; ++n)
        bf[n] = *(const i64*)(bp + (wc * 32 + n * 16 + fr) * BK + co);
      __builtin_amdgcn_s_setprio(1);
#pragma unroll
      for (int m = 0; m < 4; ++m)
#pragma unroll
        for (int n = 0; n < 2; ++n)
          acc[kt >> 2][m][n] = __builtin_amdgcn_mfma_f32_16x16x32_fp8_fp8(
              af[m], bf[n], acc[kt >> 2][m][n], 0, 0, 0);
      __builtin_amdgcn_s_setprio(0);
    }
  }
#undef STAGE

  // epilogue: recombine halves (S2 stored /256), write bf16 loc, fuse col max
#pragma unroll
  for (int n = 0; n < 2; ++n) {
    const int col = bcol + wc * 32 + n * 16 + fr;
    float cm = -3.402823466e38f;
#pragma unroll
    for (int m = 0; m < 4; ++m) {
      const int row = brow + wr * 64 + m * 16 + kg * 4;
#pragma unroll
      for (int r4 = 0; r4 < 4; ++r4) {
        float v = -0.5f * (256.0f * acc[0][m][n][r4] + acc[1][m][n][r4] +
                           qterm[row + r4]);
        loc[(size_t)(row + r4) * BB + col] = f2bf(v);
        cm = fmaxf(cm, v);
      }
    }
    cm = fmaxf(cm, __shfl_xor(cm, 16, 64));
    cm = fmaxf(cm, __shfl_xor(cm, 32, 64));
    if (kg == 0) atomicMax(&Mkey[col], fkey(cm));  // order-invariant
  }
}

// ---------------------------------------------------------------------------
// Kernel 3: wave-per-row LSE + diag + fused final mean. 512 blocks x 4 waves.
// rowval published via atomicExch (distinct addrs -> pipelined, MALL-coherent);
// hierarchical 32+1 arrive ticket (no spinning; round-2 lesson); the uniquely
// last block reads rowval with agent-scope atomic loads and writes the loss.
__global__ __launch_bounds__(256) void row_lse(
    const unsigned short* __restrict__ loc, const unsigned* __restrict__ Mkey,
    unsigned* __restrict__ rowval, unsigned* __restrict__ cnt,
    float* __restrict__ out) {
  __shared__ int lastflag;
  __shared__ float sb[4];
  const int w = threadIdx.x >> 6, lane = threadIdx.x & 63, tid = threadIdx.x;
  const int q = blockIdx.x * 4 + w;
  const short8* lp = (const short8*)(loc + (size_t)q * BB);
  const uint4* kp = (const uint4*)Mkey;
  float xs[4][8];
  float m = -3.402823466e38f, dv = 0.f;
#pragma unroll
  for (int c = 0; c < 4; ++c) {
    short8 v = lp[c * 64 + lane];
    uint4 k0 = kp[(c * 64 + lane) * 2];
    uint4 k1 = kp[(c * 64 + lane) * 2 + 1];
    unsigned ks[8] = {k0.x, k0.y, k0.z, k0.w, k1.x, k1.y, k1.z, k1.w};
#pragma unroll
    for (int e = 0; e < 8; ++e) {
      float x = bf2f((unsigned short)v[e]) - funkey(ks[e]);
      xs[c][e] = x;
      m = fmaxf(m, x);
      if (c * 512 + lane * 8 + e == q) dv = x;  // diag (static idx)
    }
  }
  m = wmax(m);
  float s = 0.f;
#pragma unroll
  for (int c = 0; c < 4; ++c)
#pragma unroll
    for (int e = 0; e < 8; ++e) s += expf(xs[c][e] - m);
  s = wsum(s);
  float d = __shfl(dv, (q >> 3) & 63, 64);
  if (lane == 0)
    atomicExch(&rowval[q], __float_as_uint(d - (m + logf(s))));

  // arrive; only the uniquely-last block continues to the final reduce
  __syncthreads();
  if (tid == 0) {
    __threadfence();
    int last = 0;
    unsigned t1 = atomicAdd(&cnt[blockIdx.x & 31], 1u);
    if (t1 == 15u) {
      unsigned t2 = atomicAdd(&cnt[32], 1u);
      last = (t2 == 31u);
    }
    lastflag = last;
  }
  __syncthreads();
  if (!lastflag) return;
  __threadfence();

  float fs = 0.f;
#pragma unroll
  for (int i = 0; i < 8; ++i) {
    unsigned u = __hip_atomic_load(&rowval[tid + i * 256], __ATOMIC_RELAXED,
                                   __HIP_MEMORY_SCOPE_AGENT);
    fs += __uint_as_float(u);
  }
  fs = wsum(fs);
  if (lane == 0) sb[w] = fs;
  __syncthreads();
  if (tid == 0) out[0] = -(sb[0] + sb[1] + sb[2] + sb[3]) * (1.0f / (float)BB);
}

// ---------------------------------------------------------------------------
extern "C" void kernel_launch(void* const* d_in, const int* in_sizes, int n_in,
                              void* d_out, int out_size, void* d_ws, size_t ws_size,
                              hipStream_t stream) {
  const float* qmean = (const float*)d_in[0];
  const float* qls   = (const float*)d_in[1];
  // d_in[2] query_z: cancels (broadcasts on target axis -> drops in colmax+softmax)
  const float* tmean = (const float*)d_in[3];
  const float* tls   = (const float*)d_in[4];
  // d_in[5] target_z: unused by reference
  const float* eps   = (const float*)d_in[6];

  char* ws = (char*)d_ws;
  unsigned char* Acat = (unsigned char*)(ws);                        // 2 MB
  unsigned char* Bcat = (unsigned char*)(ws + (2u << 20));           // 2 MB
  float* qterm   = (float*)(ws + (4u << 20));                        // 8 KB
  unsigned* Mkey = (unsigned*)(ws + (4u << 20) + 8192);              // 8 KB
  unsigned* rowval = (unsigned*)(ws + (4u << 20) + 16384);           // 8 KB
  unsigned* cnt  = (unsigned*)(ws + (4u << 20) + 24576);             // 256 B
  unsigned short* loc = (unsigned short*)(ws + (4u << 20) + 65536);  // 8 MB

  prep<<<1024, 256, 0, stream>>>(qmean, qls, tmean, tls, eps,
                                 Acat, Bcat, qterm, Mkey, cnt);
  gemm_loc<<<dim3(BB / BN, BB / BM), 256, 0, stream>>>(Acat, Bcat, qterm, loc, Mkey);
  row_lse<<<512, 256, 0, stream>>>(loc, Mkey, rowval, cnt, (float*)d_out);
}